// Round 2
// baseline (2045.291 us; speedup 1.0000x reference)
//
#include <hip/hip_runtime.h>

#define BATCH 8
#define CIN   64
#define COUT  64
#define HDIM  128
#define WDIM  128
#define HW    (HDIM * WDIM)
#define KK    9
#define QC    16          // channels per pipeline quarter
#define NSTEP (KK * 4)    // 9 taps x 4 quarters

// ---------------------------------------------------------------------------
// Kernel W: transpose weight [oc][c][k] -> Wt [k][c][oc] (coalesced staging)
// ---------------------------------------------------------------------------
__global__ __launch_bounds__(256) void transpose_w_kernel(
    const float* __restrict__ w, float* __restrict__ wt)
{
    const int i = blockIdx.x * 256 + threadIdx.x;   // 0 .. 64*64*9-1
    if (i < COUT * CIN * KK) {
        const int k = i / (CIN * COUT);
        const int r = i - k * (CIN * COUT);
        const int c = r >> 6;
        const int oc = r & 63;
        wt[i] = w[((size_t)oc * CIN + c) * KK + k];
    }
}

// ---------------------------------------------------------------------------
// Kernel A: offset conv, oc-parity split (z=0 -> dy/py, z=1 -> dx/px).
// 2x grid => 16 waves/CU; x-tap loads double-buffered (prefetch c+1).
// Weight accesses are wave-uniform -> scalar loads.
// ---------------------------------------------------------------------------
__global__ __launch_bounds__(256) void offset_conv_kernel(
    const float* __restrict__ x,
    const float* __restrict__ ow,   // [18][64][3][3]
    const float* __restrict__ ob,   // [18]
    float* __restrict__ py,         // [B][KK][HW]
    float* __restrict__ px)
{
    const int tid = threadIdx.x;
    const int pixel = blockIdx.x * 256 + tid;
    const int b = blockIdx.y;
    const int par = blockIdx.z;     // 0: even oc (dy), 1: odd oc (dx)
    const int h = pixel >> 7;
    const int w = pixel & 127;

    float acc[9];
#pragma unroll
    for (int i = 0; i < 9; ++i) acc[i] = ob[2 * i + par];

    const float* xb = x + (size_t)b * CIN * HW;

    auto loadx = [&](float* xv, int c) {
        const float* xc = xb + c * HW;
#pragma unroll
        for (int dh = 0; dh < 3; ++dh) {
            const int y = h + dh - 1;
            const bool vy = (unsigned)y < (unsigned)HDIM;
#pragma unroll
            for (int dw = 0; dw < 3; ++dw) {
                const int xw = w + dw - 1;
                const bool vx = (unsigned)xw < (unsigned)WDIM;
                float v = 0.0f;
                if (vy && vx) v = xc[y * WDIM + xw];
                xv[dh * 3 + dw] = v;
            }
        }
    };

    float xva[9], xvb[9];
    loadx(xva, 0);
    for (int c = 0; c < CIN; c += 2) {
        loadx(xvb, c + 1);
#pragma unroll
        for (int i = 0; i < 9; ++i) {
            const float* wp = ow + ((size_t)(2 * i + par) * CIN + c) * 9;
#pragma unroll
            for (int t = 0; t < 9; ++t) acc[i] = fmaf(xva[t], wp[t], acc[i]);
        }
        if (c + 2 < CIN) loadx(xva, c + 2);
#pragma unroll
        for (int i = 0; i < 9; ++i) {
            const float* wp = ow + ((size_t)(2 * i + par) * CIN + (c + 1)) * 9;
#pragma unroll
            for (int t = 0; t < 9; ++t) acc[i] = fmaf(xvb[t], wp[t], acc[i]);
        }
    }

    float* dst = par ? px : py;
#pragma unroll
    for (int i = 0; i < 9; ++i) {
        const int ki = i / 3, kj = i % 3;
        const float base = par ? (float)(w - 1 + kj) : (float)(h - 1 + ki);
        dst[((size_t)b * KK + i) * HW + pixel] = base + acc[i];
    }
}

// ---------------------------------------------------------------------------
// Kernel B: fused sampling + implicit GEMM, software-pipelined.
// Block = one output row (b,h): 128 px x 64 oc. 36 steps of 16 channels.
// Per step: issue next-quarter gather loads (regs) -> GEMM current quarter
// (hides load latency) -> blend+LDS write -> 1 barrier.
// LDS: A 2x16x128 (16KB) + W 2x16x64 (8KB) = 24.6KB -> higher occupancy.
// ---------------------------------------------------------------------------
__global__ __launch_bounds__(256, 4) void deform_main_kernel(
    const float* __restrict__ x,
    const float* __restrict__ wt,   // [k][c][oc]
    const float* __restrict__ py,
    const float* __restrict__ px,
    float* __restrict__ out)
{
    __shared__ float A_s[2][QC][WDIM];   // 16 KB
    __shared__ float W_s[2][QC][COUT];   //  8 KB

    const int tid = threadIdx.x;
    const int b = blockIdx.x >> 7;
    const int h = blockIdx.x & 127;
    const int tx = tid & 15;        // oc group: oc = tx*4..tx*4+3
    const int ty = tid >> 4;        // pix group: pix = ty*8..ty*8+7
    const int pix_g = tid & 127;    // gather pixel
    const int cg = (tid >> 7) * 8;  // gather channel offset within quarter

    float acc[8][4];
#pragma unroll
    for (int i = 0; i < 8; ++i)
#pragma unroll
        for (int j = 0; j < 4; ++j) acc[i][j] = 0.0f;

    const float* xb = x + (size_t)b * CIN * HW;
    const float* pyb = py + (size_t)b * KK * HW + h * WDIM + pix_g;
    const float* pxb = px + (size_t)b * KK * HW + h * WDIM + pix_g;

    int id0, id1, id2, id3;
    float w0, w1, w2, w3;
    auto compute_params = [&](float pyv_, float pxv_) {
        const float y0f = floorf(pyv_), x0f = floorf(pxv_);
        const float fy = pyv_ - y0f, fx = pxv_ - x0f;
        const int y0 = (int)y0f, x0 = (int)x0f;
        const int y1 = y0 + 1, x1 = x0 + 1;
        const bool vy0 = (unsigned)y0 < (unsigned)HDIM;
        const bool vy1 = (unsigned)y1 < (unsigned)HDIM;
        const bool vx0 = (unsigned)x0 < (unsigned)WDIM;
        const bool vx1 = (unsigned)x1 < (unsigned)WDIM;
        const int cy0 = min(max(y0, 0), HDIM - 1);
        const int cy1 = min(max(y1, 0), HDIM - 1);
        const int cx0 = min(max(x0, 0), WDIM - 1);
        const int cx1 = min(max(x1, 0), WDIM - 1);
        id0 = cy0 * WDIM + cx0; id1 = cy0 * WDIM + cx1;
        id2 = cy1 * WDIM + cx0; id3 = cy1 * WDIM + cx1;
        const float wy0 = 1.0f - fy, wy1 = fy;
        const float wx0 = 1.0f - fx, wx1 = fx;
        w0 = wy0 * wx0 * (float)(vy0 && vx0);
        w1 = wy0 * wx1 * (float)(vy0 && vx1);
        w2 = wy1 * wx0 * (float)(vy1 && vx0);
        w3 = wy1 * wx1 * (float)(vy1 && vx1);
    };

    // ---- prologue: params tap0, stage quarter 0 (A and W) into buffer 0
    float pyv = pyb[0], pxv = pxb[0];
    compute_params(pyv, pxv);
    {
        const float4 wst = *(const float4*)(wt + tid * 4);
        *(float4*)&W_s[0][tid >> 4][(tid & 15) * 4] = wst;
        float g[32];
#pragma unroll
        for (int i = 0; i < 8; ++i) {
            const float* xc = xb + (cg + i) * HW;
            g[i * 4 + 0] = xc[id0]; g[i * 4 + 1] = xc[id1];
            g[i * 4 + 2] = xc[id2]; g[i * 4 + 3] = xc[id3];
        }
#pragma unroll
        for (int i = 0; i < 8; ++i)
            A_s[0][cg + i][pix_g] = w0 * g[i * 4] + w1 * g[i * 4 + 1]
                                  + w2 * g[i * 4 + 2] + w3 * g[i * 4 + 3];
    }
    __syncthreads();

    // ---- main pipelined loop
    for (int s = 0; s < NSTEP; ++s) {
        const int p = s & 1;
        const int sn = s + 1;
        const bool has_next = sn < NSTEP;
        const int tn = sn >> 2, qn = sn & 3;

        float g[32];
        float4 wst;
        if (has_next) {
            if (qn == 0) compute_params(pyv, pxv);  // params for tap tn
            wst = *(const float4*)(wt + (size_t)(tn * CIN + qn * QC) * COUT + tid * 4);
            const int cb = qn * QC + cg;
#pragma unroll
            for (int i = 0; i < 8; ++i) {
                const float* xc = xb + (cb + i) * HW;
                g[i * 4 + 0] = xc[id0]; g[i * 4 + 1] = xc[id1];
                g[i * 4 + 2] = xc[id2]; g[i * 4 + 3] = xc[id3];
            }
            if (qn == 2 && tn + 1 < KK) {           // prefetch next tap's positions
                pyv = pyb[(size_t)(tn + 1) * HW];
                pxv = pxb[(size_t)(tn + 1) * HW];
            }
        }

        // GEMM on current quarter (overlaps the in-flight gather loads)
#pragma unroll
        for (int c = 0; c < QC; ++c) {
            const float4 a0 = *(const float4*)&A_s[p][c][ty * 8];
            const float4 a1 = *(const float4*)&A_s[p][c][ty * 8 + 4];
            const float4 wv = *(const float4*)&W_s[p][c][tx * 4];
            const float av[8] = {a0.x, a0.y, a0.z, a0.w, a1.x, a1.y, a1.z, a1.w};
            const float wj[4] = {wv.x, wv.y, wv.z, wv.w};
#pragma unroll
            for (int i = 0; i < 8; ++i)
#pragma unroll
                for (int j = 0; j < 4; ++j)
                    acc[i][j] = fmaf(av[i], wj[j], acc[i][j]);
        }

        if (has_next) {
#pragma unroll
            for (int i = 0; i < 8; ++i)
                A_s[p ^ 1][cg + i][pix_g] = w0 * g[i * 4] + w1 * g[i * 4 + 1]
                                          + w2 * g[i * 4 + 2] + w3 * g[i * 4 + 3];
            *(float4*)&W_s[p ^ 1][tid >> 4][(tid & 15) * 4] = wst;
        }
        __syncthreads();
    }

    // ---- epilogue: coalesced float4 stores
    float* ob = out + (size_t)b * COUT * HW + (size_t)h * WDIM;
#pragma unroll
    for (int j = 0; j < 4; ++j) {
        const int oc = tx * 4 + j;
        const float4 v0 = make_float4(acc[0][j], acc[1][j], acc[2][j], acc[3][j]);
        const float4 v1 = make_float4(acc[4][j], acc[5][j], acc[6][j], acc[7][j]);
        *(float4*)(ob + (size_t)oc * HW + ty * 8)     = v0;
        *(float4*)(ob + (size_t)oc * HW + ty * 8 + 4) = v1;
    }
}

// ---------------------------------------------------------------------------
extern "C" void kernel_launch(void* const* d_in, const int* in_sizes, int n_in,
                              void* d_out, int out_size, void* d_ws, size_t ws_size,
                              hipStream_t stream)
{
    const float* x  = (const float*)d_in[0];
    const float* ow = (const float*)d_in[1];
    const float* ob = (const float*)d_in[2];
    const float* wgt = (const float*)d_in[3];
    float* out = (float*)d_out;

    // ws layout: py | px | Wt   (~9.6 MB)
    float* py = (float*)d_ws;
    float* px = py + (size_t)BATCH * KK * HW;
    float* wt = px + (size_t)BATCH * KK * HW;

    transpose_w_kernel<<<dim3((COUT * CIN * KK + 255) / 256), 256, 0, stream>>>(wgt, wt);

    dim3 gridA(HW / 256, BATCH, 2);
    offset_conv_kernel<<<gridA, 256, 0, stream>>>(x, ow, ob, py, px);

    deform_main_kernel<<<dim3(BATCH * HDIM), 256, 0, stream>>>(x, wt, py, px, out);
}

// Round 3
// 371.848 us; speedup vs baseline: 5.5003x; 5.5003x over previous
//
#include <hip/hip_runtime.h>

#define BATCH 8
#define CIN   64
#define COUT  64
#define HDIM  128
#define WDIM  128
#define HW    (HDIM * WDIM)
#define KK    9
#define QC    8           // channels per pipeline step
#define NSTEP (KK * 8)    // 9 taps x 8 channel-groups = 72

// ---------------------------------------------------------------------------
// Kernel W: transpose weight [oc][c][k] -> Wt [k][c][oc]
// ---------------------------------------------------------------------------
__global__ __launch_bounds__(256) void transpose_w_kernel(
    const float* __restrict__ w, float* __restrict__ wt)
{
    const int i = blockIdx.x * 256 + threadIdx.x;   // 0 .. 64*64*9-1
    if (i < COUT * CIN * KK) {
        const int k = i / (CIN * COUT);
        const int r = i - k * (CIN * COUT);
        const int c = r >> 6;
        const int oc = r & 63;
        wt[i] = w[((size_t)oc * CIN + c) * KK + k];
    }
}

// ---------------------------------------------------------------------------
// Kernel A: offset conv, oc-parity split (z=0 -> dy/py, z=1 -> dx/px).
// ---------------------------------------------------------------------------
__global__ __launch_bounds__(256) void offset_conv_kernel(
    const float* __restrict__ x,
    const float* __restrict__ ow,   // [18][64][3][3]
    const float* __restrict__ ob,   // [18]
    float* __restrict__ py,         // [B][KK][HW]
    float* __restrict__ px)
{
    const int tid = threadIdx.x;
    const int pixel = blockIdx.x * 256 + tid;
    const int b = blockIdx.y;
    const int par = blockIdx.z;     // 0: even oc (dy), 1: odd oc (dx)
    const int h = pixel >> 7;
    const int w = pixel & 127;

    float acc[9];
#pragma unroll
    for (int i = 0; i < 9; ++i) acc[i] = ob[2 * i + par];

    const float* xb = x + (size_t)b * CIN * HW;

    auto loadx = [&](float* xv, int c) {
        const float* xc = xb + c * HW;
#pragma unroll
        for (int dh = 0; dh < 3; ++dh) {
            const int y = h + dh - 1;
            const bool vy = (unsigned)y < (unsigned)HDIM;
#pragma unroll
            for (int dw = 0; dw < 3; ++dw) {
                const int xw = w + dw - 1;
                const bool vx = (unsigned)xw < (unsigned)WDIM;
                float v = 0.0f;
                if (vy && vx) v = xc[y * WDIM + xw];
                xv[dh * 3 + dw] = v;
            }
        }
    };

    float xva[9], xvb[9];
    loadx(xva, 0);
    for (int c = 0; c < CIN; c += 2) {
        loadx(xvb, c + 1);
#pragma unroll
        for (int i = 0; i < 9; ++i) {
            const float* wp = ow + ((size_t)(2 * i + par) * CIN + c) * 9;
#pragma unroll
            for (int t = 0; t < 9; ++t) acc[i] = fmaf(xva[t], wp[t], acc[i]);
        }
        if (c + 2 < CIN) loadx(xva, c + 2);
#pragma unroll
        for (int i = 0; i < 9; ++i) {
            const float* wp = ow + ((size_t)(2 * i + par) * CIN + (c + 1)) * 9;
#pragma unroll
            for (int t = 0; t < 9; ++t) acc[i] = fmaf(xvb[t], wp[t], acc[i]);
        }
    }

    float* dst = par ? px : py;
#pragma unroll
    for (int i = 0; i < 9; ++i) {
        const int ki = i / 3, kj = i % 3;
        const float base = par ? (float)(w - 1 + kj) : (float)(h - 1 + ki);
        dst[((size_t)b * KK + i) * HW + pixel] = base + acc[i];
    }
}

// ---------------------------------------------------------------------------
// Kernel B v3: fused sampling + implicit GEMM, software-pipelined.
// Block = 512 threads (8 waves) covering 2 rows (256 px) x 64 oc.
// Wave w owns oc-group w (8 oc); lane owns 4 consecutive px -> acc[4][8].
// W read via wave-uniform scalar loads (s_load) -> LDS carries only A.
// Per step: gather next 8-channel group (16 loads/thread, in-flight regs)
// -> GEMM current group (hides latency) -> blend+LDS write -> 1 barrier.
// ---------------------------------------------------------------------------
__global__ __launch_bounds__(512)
__attribute__((amdgpu_waves_per_eu(4, 4)))
void deform_main_kernel(
    const float* __restrict__ x,
    const float* __restrict__ wt,   // [k][c][oc]
    const float* __restrict__ py,
    const float* __restrict__ px,
    float* __restrict__ out)
{
    __shared__ float A_s[2][QC][256];   // 16 KB

    const int tid = threadIdx.x;
    const int b = blockIdx.x >> 6;            // 512 blocks: b in 0..7
    const int h0 = (blockIdx.x & 63) * 2;     // row pair
    const int lane = tid & 63;
    const int ocg = __builtin_amdgcn_readfirstlane(tid >> 6);  // uniform wave id
    const int pix_g = tid & 255;              // gather pixel (0..255, 2 rows)
    const int cgrp4 = (tid >> 8) * 4;         // 0 or 4: channel sub-group

    float acc[4][8];
#pragma unroll
    for (int i = 0; i < 4; ++i)
#pragma unroll
        for (int j = 0; j < 8; ++j) acc[i][j] = 0.0f;

    const char* xb = (const char*)(x + (size_t)b * CIN * HW);
    const float* pyb = py + (size_t)b * KK * HW + h0 * WDIM + pix_g;
    const float* pxb = px + (size_t)b * KK * HW + h0 * WDIM + pix_g;

    int   idb0, idb1, idb2, idb3;   // byte offsets of 4 bilinear corners
    float w0, w1, w2, w3;           // bilinear weights (validity folded in)
    auto compute_params = [&](float pyv_, float pxv_) {
        const float y0f = floorf(pyv_), x0f = floorf(pxv_);
        const float fy = pyv_ - y0f, fx = pxv_ - x0f;
        const int y0 = (int)y0f, x0 = (int)x0f;
        const int y1 = y0 + 1, x1 = x0 + 1;
        const bool vy0 = (unsigned)y0 < (unsigned)HDIM;
        const bool vy1 = (unsigned)y1 < (unsigned)HDIM;
        const bool vx0 = (unsigned)x0 < (unsigned)WDIM;
        const bool vx1 = (unsigned)x1 < (unsigned)WDIM;
        const int cy0 = min(max(y0, 0), HDIM - 1);
        const int cy1 = min(max(y1, 0), HDIM - 1);
        const int cx0 = min(max(x0, 0), WDIM - 1);
        const int cx1 = min(max(x1, 0), WDIM - 1);
        idb0 = (cy0 * WDIM + cx0) * 4;  idb1 = (cy0 * WDIM + cx1) * 4;
        idb2 = (cy1 * WDIM + cx0) * 4;  idb3 = (cy1 * WDIM + cx1) * 4;
        const float wy0 = 1.0f - fy, wy1 = fy;
        const float wx0 = 1.0f - fx, wx1 = fx;
        w0 = wy0 * wx0 * (float)(vy0 && vx0);
        w1 = wy0 * wx1 * (float)(vy0 && vx1);
        w2 = wy1 * wx0 * (float)(vy1 && vx0);
        w3 = wy1 * wx1 * (float)(vy1 && vx1);
    };

    // ---- prologue: stage tap 0, channel-group 0 into buffer 0
    float pyv = pyb[0], pxv = pxb[0];
    compute_params(pyv, pxv);
    {
#pragma unroll
        for (int i = 0; i < 4; ++i) {
            const char* xc = xb + (size_t)(cgrp4 + i) * (HW * 4);
            float v = *(const float*)(xc + idb0) * w0;
            v = fmaf(*(const float*)(xc + idb1), w1, v);
            v = fmaf(*(const float*)(xc + idb2), w2, v);
            v = fmaf(*(const float*)(xc + idb3), w3, v);
            A_s[0][cgrp4 + i][pix_g] = v;
        }
    }
    __syncthreads();

    // ---- main pipelined loop: 72 steps of 8 channels
    for (int s = 0; s < NSTEP; ++s) {
        const int p = s & 1;
        const int sn = s + 1;
        const int tn = sn >> 3, qn = sn & 7;
        const bool hn = sn < NSTEP;

        // issue next group's 16 scattered gather loads (stay in flight)
        float g[16];
        if (hn) {
            if (qn == 0) compute_params(pyv, pxv);  // params for tap tn
            const char* xq = xb + (size_t)(qn * QC + cgrp4) * (HW * 4);
#pragma unroll
            for (int i = 0; i < 4; ++i) {
                const char* xc = xq + (size_t)i * (HW * 4);
                g[i * 4 + 0] = *(const float*)(xc + idb0);
                g[i * 4 + 1] = *(const float*)(xc + idb1);
                g[i * 4 + 2] = *(const float*)(xc + idb2);
                g[i * 4 + 3] = *(const float*)(xc + idb3);
            }
            if (qn == 6 && tn + 1 < KK) {   // prefetch next tap's positions
                pyv = pyb[(size_t)(tn + 1) * HW];
                pxv = pxb[(size_t)(tn + 1) * HW];
            }
        }

        // GEMM on current group: A from LDS, W from scalar (uniform) loads
        {
            const int ks = s >> 3, qs = s & 7;
            const float* wq = wt + ((size_t)ks * CIN + qs * QC) * COUT + ocg * 8;
#pragma unroll
            for (int c = 0; c < QC; ++c) {
                const float4 a = *(const float4*)&A_s[p][c][lane * 4];
#pragma unroll
                for (int j = 0; j < 8; ++j) {
                    const float wv = wq[c * COUT + j];   // s_load (uniform)
                    acc[0][j] = fmaf(a.x, wv, acc[0][j]);
                    acc[1][j] = fmaf(a.y, wv, acc[1][j]);
                    acc[2][j] = fmaf(a.z, wv, acc[2][j]);
                    acc[3][j] = fmaf(a.w, wv, acc[3][j]);
                }
            }
        }

        // blend gathered values, write into the other buffer
        if (hn) {
#pragma unroll
            for (int i = 0; i < 4; ++i) {
                float v = g[i * 4 + 0] * w0;
                v = fmaf(g[i * 4 + 1], w1, v);
                v = fmaf(g[i * 4 + 2], w2, v);
                v = fmaf(g[i * 4 + 3], w3, v);
                A_s[p ^ 1][cgrp4 + i][pix_g] = v;
            }
        }
        __syncthreads();
    }

    // ---- epilogue: coalesced float4 stores (1 KB per wave per oc)
#pragma unroll
    for (int j = 0; j < 8; ++j) {
        float* op = out + ((size_t)b * COUT + ocg * 8 + j) * HW
                        + h0 * WDIM + lane * 4;
        *(float4*)op = make_float4(acc[0][j], acc[1][j], acc[2][j], acc[3][j]);
    }
}

// ---------------------------------------------------------------------------
extern "C" void kernel_launch(void* const* d_in, const int* in_sizes, int n_in,
                              void* d_out, int out_size, void* d_ws, size_t ws_size,
                              hipStream_t stream)
{
    const float* x   = (const float*)d_in[0];
    const float* ow  = (const float*)d_in[1];
    const float* ob  = (const float*)d_in[2];
    const float* wgt = (const float*)d_in[3];
    float* out = (float*)d_out;

    // ws layout: py | px | Wt
    float* py = (float*)d_ws;
    float* px = py + (size_t)BATCH * KK * HW;
    float* wt = px + (size_t)BATCH * KK * HW;

    transpose_w_kernel<<<dim3((COUT * CIN * KK + 255) / 256), 256, 0, stream>>>(wgt, wt);

    dim3 gridA(HW / 256, BATCH, 2);
    offset_conv_kernel<<<gridA, 256, 0, stream>>>(x, ow, ob, py, px);

    deform_main_kernel<<<dim3(BATCH * HDIM / 2), 512, 0, stream>>>(x, wt, py, px, out);
}